// Round 4
// baseline (453.664 us; speedup 1.0000x reference)
//
#include <hip/hip_runtime.h>

#define NUM_ENT 200000
#define BQ 128
#define DIM 128
#define NE 2     // entities per thread (acc rows)
#define TBQ 16   // queries per block (BQ/TBQ = gridDim.y = 8)

// Kernel 1: query[b][d] = E[h[b]][d] + R[r[b]][d] + T[t[b]][d]
__global__ void build_query_kernel(const float* __restrict__ ent,
                                   const float* __restrict__ rel,
                                   const float* __restrict__ tim,
                                   const int* __restrict__ h_idx,
                                   const int* __restrict__ r_idx,
                                   const int* __restrict__ t_idx,
                                   float* __restrict__ q) {
    const int b = blockIdx.x;
    const int d = threadIdx.x;
    q[b * DIM + d] = ent[(size_t)h_idx[b] * DIM + d]
                   + rel[(size_t)r_idx[b] * DIM + d]
                   + tim[(size_t)t_idx[b] * DIM + d];
}

// Kernel 2: each thread scores NE=2 entities x TBQ=16 queries.
// acc = 32 VGPR, e-chunks = 16 VGPR -> no spill, high occupancy.
// q loads are wave-uniform -> s_load; e rows per-lane (coalesced stores in n).
__global__ __launch_bounds__(256) void score_kernel(
        const float* __restrict__ ent,
        const float* __restrict__ q,
        float* __restrict__ out) {
    const int tid = threadIdx.x;
    const int n0 = blockIdx.x * (256 * NE) + tid;   // rows n0 + ne*256
    const int qt = blockIdx.y * TBQ;

    // Hoisted, clamped row pointers (only last x-block clamps).
    const float* __restrict__ erow[NE];
#pragma unroll
    for (int ne = 0; ne < NE; ++ne) {
        int n = n0 + ne * 256;
        int nc = (n < NUM_ENT) ? n : (NUM_ENT - 1);
        erow[ne] = ent + (size_t)nc * DIM;
    }

    float acc[NE][TBQ];
#pragma unroll
    for (int ne = 0; ne < NE; ++ne)
#pragma unroll
        for (int tb = 0; tb < TBQ; ++tb) acc[ne][tb] = 0.0f;

    const float* __restrict__ qbase = q + qt * DIM;

    for (int dc = 0; dc < DIM; dc += 8) {
        float4 e0[NE], e1[NE];
#pragma unroll
        for (int ne = 0; ne < NE; ++ne) {
            e0[ne] = *(const float4*)(erow[ne] + dc);
            e1[ne] = *(const float4*)(erow[ne] + dc + 4);
        }
#pragma unroll
        for (int tb = 0; tb < TBQ; ++tb) {
            const float* qp = qbase + tb * DIM + dc;
            float4 q0 = *(const float4*)(qp);
            float4 q1 = *(const float4*)(qp + 4);
#pragma unroll
            for (int ne = 0; ne < NE; ++ne) {
                float d0 = fabsf(q0.x - e0[ne].x);
                float d1 = fabsf(q0.y - e0[ne].y);
                float d2 = fabsf(q0.z - e0[ne].z);
                float d3 = fabsf(q0.w - e0[ne].w);
                float d4 = fabsf(q1.x - e1[ne].x);
                float d5 = fabsf(q1.y - e1[ne].y);
                float d6 = fabsf(q1.z - e1[ne].z);
                float d7 = fabsf(q1.w - e1[ne].w);
                acc[ne][tb] += ((d0 + d1) + (d2 + d3)) + ((d4 + d5) + (d6 + d7));
            }
        }
    }

#pragma unroll
    for (int ne = 0; ne < NE; ++ne) {
        int n = n0 + ne * 256;
        if (n < NUM_ENT) {
#pragma unroll
            for (int tb = 0; tb < TBQ; ++tb)
                out[(size_t)(qt + tb) * NUM_ENT + n] = -acc[ne][tb];
        }
    }
}

extern "C" void kernel_launch(void* const* d_in, const int* in_sizes, int n_in,
                              void* d_out, int out_size, void* d_ws, size_t ws_size,
                              hipStream_t stream) {
    const float* ent = (const float*)d_in[0];
    const float* rel = (const float*)d_in[1];
    const float* tim = (const float*)d_in[2];
    const int*   h_idx = (const int*)d_in[3];
    const int*   r_idx = (const int*)d_in[4];
    const int*   t_idx = (const int*)d_in[5];
    float* out = (float*)d_out;
    float* q   = (float*)d_ws;   // 128*128 f32 = 64 KB scratch

    build_query_kernel<<<BQ, DIM, 0, stream>>>(ent, rel, tim, h_idx, r_idx, t_idx, q);

    const int nblocks = (NUM_ENT + 256 * NE - 1) / (256 * NE);   // 391
    dim3 grid(nblocks, BQ / TBQ);                                 // (391, 8)
    score_kernel<<<grid, 256, 0, stream>>>(ent, q, out);
}

// Round 6
// 196.741 us; speedup vs baseline: 2.3059x; 2.3059x over previous
//
#include <hip/hip_runtime.h>

#define NUM_ENT 200000
#define BQ 128
#define DIM 128
#define EN 128     // entity rows per block tile (staged in LDS as f16)
#define QT 64      // queries per block  (gridDim.y = BQ/QT = 2)
#define QW 16      // queries per wave   (4 waves/block)

typedef __fp16 h2 __attribute__((ext_vector_type(2)));   // matches builtin 'V2h'
typedef __attribute__((ext_vector_type(4))) unsigned int uint4v;

static __device__ __forceinline__ unsigned int pkrtz_u(float a, float b) {
    h2 h = __builtin_amdgcn_cvt_pkrtz(a, b);
    return __builtin_bit_cast(unsigned int, h);
}
static __device__ __forceinline__ h2 u_h2(unsigned int u) {
    return __builtin_bit_cast(h2, u);
}
static __device__ __forceinline__ h2 habs2(h2 x) {
    unsigned int u = __builtin_bit_cast(unsigned int, x) & 0x7FFF7FFFu;
    return __builtin_bit_cast(h2, u);
}

#if __has_builtin(__builtin_amdgcn_fdot2)
static __device__ __forceinline__ float fdot2(h2 a, h2 b, float c) {
    return __builtin_amdgcn_fdot2(a, b, c, false);
}
#else
static __device__ __forceinline__ float fdot2(h2 a, h2 b, float c) {
    return c + (float)a[0] * (float)b[0] + (float)a[1] * (float)b[1];
}
#endif

// Kernel 1: q16[b][d/2] = pack_f16(E[h]+R[r]+T[t]) — 128 blocks x 64 threads
__global__ void build_query_kernel(const float* __restrict__ ent,
                                   const float* __restrict__ rel,
                                   const float* __restrict__ tim,
                                   const int* __restrict__ h_idx,
                                   const int* __restrict__ r_idx,
                                   const int* __restrict__ t_idx,
                                   unsigned int* __restrict__ q16) {
    const int b = blockIdx.x, i = threadIdx.x;
    const int d = i * 2;
    const float* eh = ent + (size_t)h_idx[b] * DIM;
    const float* rr = rel + (size_t)r_idx[b] * DIM;
    const float* tt = tim + (size_t)t_idx[b] * DIM;
    float x0 = eh[d] + rr[d] + tt[d];
    float x1 = eh[d + 1] + rr[d + 1] + tt[d + 1];
    q16[b * (DIM / 2) + i] = pkrtz_u(x0, x1);
}

// Kernel 2: block stages 128 entity rows (f32->f16, XOR-swizzled) into LDS
// with coalesced global loads, then each thread scores 2 entities x 16 queries
// via packed-f16 |q-e| + v_dot2_f32_f16 accumulation.
__global__ __launch_bounds__(256) void score_kernel(
        const float* __restrict__ ent,
        const unsigned int* __restrict__ q16,
        float* __restrict__ out) {
    __shared__ __align__(16) unsigned int lds[EN * 64];  // 128 rows * 256B (f16)

    const int tid = threadIdx.x;
    const int n0 = blockIdx.x * EN;
    const int qt = blockIdx.y * QT;

    // ---- stage: 64KB f32 (contiguous rows) -> 32KB f16 LDS, swizzled ----
#pragma unroll
    for (int p = 0; p < 4; ++p) {
        const int tt = tid + p * 256;
        const int r = tt >> 3;        // row 0..127
        const int sub = tt & 7;       // 16-float sub-chunk within row
        int n = n0 + r;
        if (n >= NUM_ENT) n = NUM_ENT - 1;
        const float* gp = ent + (size_t)n * DIM + sub * 16;
        float4 a = *(const float4*)(gp);
        float4 b = *(const float4*)(gp + 4);
        float4 c = *(const float4*)(gp + 8);
        float4 d = *(const float4*)(gp + 12);
        uint4v w0 = { pkrtz_u(a.x, a.y), pkrtz_u(a.z, a.w),
                      pkrtz_u(b.x, b.y), pkrtz_u(b.z, b.w) };
        uint4v w1 = { pkrtz_u(c.x, c.y), pkrtz_u(c.z, c.w),
                      pkrtz_u(d.x, d.y), pkrtz_u(d.z, d.w) };
        const int c16 = sub * 2;      // 16B slot index (0..15)
        const int k = r & 7;          // swizzle key
        *(uint4v*)&lds[r * 64 + ((c16    ) ^ k) * 4] = w0;
        *(uint4v*)&lds[r * 64 + ((c16 + 1) ^ k) * 4] = w1;
    }
    __syncthreads();

    // ---- compute ----
    const int lane = tid & 63;
    const int wave = tid >> 6;
    const h2* __restrict__ qbase = (const h2*)q16 + (qt + wave * QW) * (DIM / 2);
    const int k = lane & 7;           // same swizzle key for both ne rows

    float acc[2][QW];
#pragma unroll
    for (int ne = 0; ne < 2; ++ne)
#pragma unroll
        for (int tb = 0; tb < QW; ++tb) acc[ne][tb] = 0.0f;

    const h2 one = { (__fp16)1.0f, (__fp16)1.0f };

    for (int dc = 0; dc < DIM; dc += 8) {    // 8 dims = one 16B f16 slot
        const int c16 = dc >> 3;
        uint4v e[2];
#pragma unroll
        for (int ne = 0; ne < 2; ++ne) {
            const int r = lane + ne * 64;
            e[ne] = *(const uint4v*)&lds[r * 64 + (c16 ^ k) * 4];
        }
#pragma unroll
        for (int tb = 0; tb < QW; ++tb) {
            const h2* qp = qbase + tb * (DIM / 2) + (dc >> 1);
            h2 q0 = qp[0], q1 = qp[1], q2 = qp[2], q3 = qp[3];
#pragma unroll
            for (int ne = 0; ne < 2; ++ne) {
                h2 e0 = u_h2(e[ne][0]), e1 = u_h2(e[ne][1]);
                h2 e2 = u_h2(e[ne][2]), e3 = u_h2(e[ne][3]);
                acc[ne][tb] = fdot2(habs2(q0 - e0), one, acc[ne][tb]);
                acc[ne][tb] = fdot2(habs2(q1 - e1), one, acc[ne][tb]);
                acc[ne][tb] = fdot2(habs2(q2 - e2), one, acc[ne][tb]);
                acc[ne][tb] = fdot2(habs2(q3 - e3), one, acc[ne][tb]);
            }
        }
    }

    // ---- store: lane -> entity (coalesced dwords) ----
#pragma unroll
    for (int ne = 0; ne < 2; ++ne) {
        const int n = n0 + lane + ne * 64;
        if (n < NUM_ENT) {
#pragma unroll
            for (int tb = 0; tb < QW; ++tb)
                out[(size_t)(qt + wave * QW + tb) * NUM_ENT + n] = -acc[ne][tb];
        }
    }
}

extern "C" void kernel_launch(void* const* d_in, const int* in_sizes, int n_in,
                              void* d_out, int out_size, void* d_ws, size_t ws_size,
                              hipStream_t stream) {
    const float* ent = (const float*)d_in[0];
    const float* rel = (const float*)d_in[1];
    const float* tim = (const float*)d_in[2];
    const int*   h_idx = (const int*)d_in[3];
    const int*   r_idx = (const int*)d_in[4];
    const int*   t_idx = (const int*)d_in[5];
    float* out = (float*)d_out;
    unsigned int* q16 = (unsigned int*)d_ws;   // 128 x 64 dwords = 32 KB

    build_query_kernel<<<BQ, 64, 0, stream>>>(ent, rel, tim, h_idx, r_idx, t_idx, q16);

    const int nblocks = (NUM_ENT + EN - 1) / EN;   // 1563
    dim3 grid(nblocks, BQ / QT);                   // (1563, 2)
    score_kernel<<<grid, 256, 0, stream>>>(ent, q16, out);
}